// Round 1
// baseline (538.230 us; speedup 1.0000x reference)
//
#include <hip/hip_runtime.h>

// Problem constants (fixed by reference): B=2, T=2048, C=1024, H=16, S=64
#define BB 2
#define TT 2048
#define CC 1024
#define HH 16
#define SS 64
#define MM (BB * TT)   // 4096 rows in all GEMMs

typedef unsigned short u16;
typedef __bf16 bf16x8 __attribute__((ext_vector_type(8)));
typedef float f32x4 __attribute__((ext_vector_type(4)));

#define MFMA16(a, b, c) __builtin_amdgcn_mfma_f32_16x16x32_bf16((a), (b), (c), 0, 0, 0)

__device__ inline u16 f2bf(float f) {
    union { float f; unsigned u; } v;
    v.f = f;
    unsigned r = v.u + 0x7FFFu + ((v.u >> 16) & 1u);
    return (u16)(r >> 16);
}

// ---------------------------------------------------------------- cast fp32 -> bf16
__global__ __launch_bounds__(256) void cast_f32_bf16(const float4* __restrict__ in,
                                                     ushort4* __restrict__ out, int n4) {
    int i = blockIdx.x * 256 + threadIdx.x;
    if (i < n4) {
        float4 v = in[i];
        ushort4 r;
        r.x = f2bf(v.x); r.y = f2bf(v.y); r.z = f2bf(v.z); r.w = f2bf(v.w);
        out[i] = r;
    }
}

// ---------------------------------------------------------------- GEMM: C = A * Bt^T
// A: [MM][CC] bf16 row-major. Bt: [CC][CC] bf16 row-major (nn.Linear weight, y = x@W.T).
// MODE 0: bf16 out row-major [MM][CC], scaled.
// MODE 1: bf16 out TRANSPOSED [CC][MM] (for V).
// MODE 2: f32 out row-major + bias (final projection).
// Each wave computes a 16x64 output tile. mt = MM/16 = 256, nt = CC/64 = 16.
template <int MODE>
__global__ __launch_bounds__(256) void gemm_bt(const u16* __restrict__ A,
                                               const u16* __restrict__ Bt,
                                               void* __restrict__ Cout,
                                               float scale,
                                               const float* __restrict__ bias) {
    int lane = threadIdx.x & 63;
    int wid = (blockIdx.x * 256 + threadIdx.x) >> 6;
    int row_t = wid & 255;         // MM/16 - 1
    int col_t = wid >> 8;          // 0..15
    int l15 = lane & 15;
    int ko = (lane >> 4) * 8;

    const long arow = (long)(row_t * 16 + l15) * CC + ko;
    const long bbase = (long)(col_t * 64 + l15) * CC + ko;

    f32x4 acc[4];
#pragma unroll
    for (int j = 0; j < 4; ++j) acc[j] = (f32x4){0.f, 0.f, 0.f, 0.f};

    for (int k0 = 0; k0 < CC; k0 += 32) {
        bf16x8 af = *(const bf16x8*)(A + arow + k0);
#pragma unroll
        for (int j = 0; j < 4; ++j) {
            bf16x8 bf = *(const bf16x8*)(Bt + bbase + (long)j * 16 * CC + k0);
            acc[j] = MFMA16(af, bf, acc[j]);
        }
    }

    int r0 = row_t * 16 + ((lane >> 4) << 2);
    int c0 = col_t * 64 + l15;
    if (MODE == 2) {
        float* C = (float*)Cout;
#pragma unroll
        for (int j = 0; j < 4; ++j) {
            int c = c0 + j * 16;
            float bv = bias[c];
#pragma unroll
            for (int i = 0; i < 4; ++i)
                C[(long)(r0 + i) * CC + c] = acc[j][i] * scale + bv;
        }
    } else if (MODE == 0) {
        u16* C = (u16*)Cout;
#pragma unroll
        for (int j = 0; j < 4; ++j) {
            int c = c0 + j * 16;
#pragma unroll
            for (int i = 0; i < 4; ++i)
                C[(long)(r0 + i) * CC + c] = f2bf(acc[j][i] * scale);
        }
    } else {  // MODE 1: transposed store Ct[n][m], ld = MM
        u16* C = (u16*)Cout;
#pragma unroll
        for (int j = 0; j < 4; ++j) {
            int c = c0 + j * 16;
#pragma unroll
            for (int i = 0; i < 4; ++i)
                C[(long)c * MM + (r0 + i)] = f2bf(acc[j][i] * scale);
        }
    }
}

// ---------------------------------------------------------------- flash attention
// Q, K: [MM][CC] bf16 (Q pre-scaled by 1/8). Vt: [CC][MM] bf16 transposed.
// O: [MM][CC] bf16. One wave handles 16 query rows of one (b,h); KV blocks of 32.
__global__ __launch_bounds__(256) void attn_fwd(const u16* __restrict__ Q,
                                                const u16* __restrict__ Kb,
                                                const u16* __restrict__ Vt,
                                                u16* __restrict__ O) {
    __shared__ u16 Plds[4][16 * 32];
    int lane = threadIdx.x & 63;
    int wloc = threadIdx.x >> 6;
    int wave = blockIdx.x * 4 + wloc;
    int qt = wave & 127;       // T/16 - 1
    int bh = wave >> 7;        // 0..31
    int h = bh & 15;
    int b = bh >> 4;
    int q0 = qt << 4;
    int l15 = lane & 15;
    int ko = (lane >> 4) * 8;

    const long rowQ = (long)(b * TT + q0 + l15) * CC + h * SS;
    bf16x8 qf0 = *(const bf16x8*)(Q + rowQ + ko);
    bf16x8 qf1 = *(const bf16x8*)(Q + rowQ + 32 + ko);

    f32x4 oa[4];
    float mr[4], lr[4];
#pragma unroll
    for (int j = 0; j < 4; ++j) oa[j] = (f32x4){0.f, 0.f, 0.f, 0.f};
#pragma unroll
    for (int i = 0; i < 4; ++i) { mr[i] = -1e30f; lr[i] = 0.f; }

    u16* P = Plds[wloc];
    int nblk = ((q0 + 15) >> 5) + 1;

    for (int blk = 0; blk < nblk; ++blk) {
        int kv0 = blk << 5;
        f32x4 s0 = (f32x4){0.f, 0.f, 0.f, 0.f};
        f32x4 s1 = (f32x4){0.f, 0.f, 0.f, 0.f};
        const long rowK = (long)(b * TT + kv0 + l15) * CC + h * SS + ko;
        bf16x8 kf;
        kf = *(const bf16x8*)(Kb + rowK);                  s0 = MFMA16(qf0, kf, s0);
        kf = *(const bf16x8*)(Kb + rowK + 32);             s0 = MFMA16(qf1, kf, s0);
        kf = *(const bf16x8*)(Kb + rowK + 16 * CC);        s1 = MFMA16(qf0, kf, s1);
        kf = *(const bf16x8*)(Kb + rowK + 16 * CC + 32);   s1 = MFMA16(qf1, kf, s1);

        if (kv0 + 31 > q0) {  // causal mask needed in this block
            int qrow = q0 + ((lane >> 4) << 2);
            int kc = kv0 + l15;
#pragma unroll
            for (int i = 0; i < 4; ++i) {
                if (kc > qrow + i) s0[i] = -1e30f;
                if (kc + 16 > qrow + i) s1[i] = -1e30f;
            }
        }

#pragma unroll
        for (int i = 0; i < 4; ++i) {
            float mx = fmaxf(s0[i], s1[i]);
            mx = fmaxf(mx, __shfl_xor(mx, 1));
            mx = fmaxf(mx, __shfl_xor(mx, 2));
            mx = fmaxf(mx, __shfl_xor(mx, 4));
            mx = fmaxf(mx, __shfl_xor(mx, 8));
            float mnew = fmaxf(mr[i], mx);
            float scl = __expf(mr[i] - mnew);
            float p0 = __expf(s0[i] - mnew);
            float p1 = __expf(s1[i] - mnew);
            float rs = p0 + p1;
            rs += __shfl_xor(rs, 1);
            rs += __shfl_xor(rs, 2);
            rs += __shfl_xor(rs, 4);
            rs += __shfl_xor(rs, 8);
            lr[i] = lr[i] * scl + rs;
            mr[i] = mnew;
            oa[0][i] *= scl; oa[1][i] *= scl; oa[2][i] *= scl; oa[3][i] *= scl;
            int prow = ((lane >> 4) << 2) + i;
            P[prow * 32 + l15] = f2bf(p0);
            P[prow * 32 + 16 + l15] = f2bf(p1);
        }
        asm volatile("s_waitcnt lgkmcnt(0)" ::: "memory");

        bf16x8 pf = *(const bf16x8*)(P + l15 * 32 + ko);
        const long vbase = (long)(h * SS + l15) * MM + b * TT + kv0 + ko;
#pragma unroll
        for (int j = 0; j < 4; ++j) {
            bf16x8 vf = *(const bf16x8*)(Vt + vbase + (long)j * 16 * MM);
            oa[j] = MFMA16(pf, vf, oa[j]);
        }
    }

#pragma unroll
    for (int i = 0; i < 4; ++i) {
        float inv = 1.0f / lr[i];
        int trow = q0 + ((lane >> 4) << 2) + i;
        long obase = (long)(b * TT + trow) * CC + h * SS + l15;
        O[obase + 0]  = f2bf(oa[0][i] * inv);
        O[obase + 16] = f2bf(oa[1][i] * inv);
        O[obase + 32] = f2bf(oa[2][i] * inv);
        O[obase + 48] = f2bf(oa[3][i] * inv);
    }
}

// ---------------------------------------------------------------- launch
extern "C" void kernel_launch(void* const* d_in, const int* in_sizes, int n_in,
                              void* d_out, int out_size, void* d_ws, size_t ws_size,
                              hipStream_t stream) {
    const float* x  = (const float*)d_in[0];
    const float* Wq = (const float*)d_in[1];
    const float* Wk = (const float*)d_in[2];
    const float* Wv = (const float*)d_in[3];
    const float* Wo = (const float*)d_in[4];
    const float* bo = (const float*)d_in[5];

    char* ws = (char*)d_ws;
    const size_t MB = 1024 * 1024;
    u16* x_bf   = (u16*)(ws);                 // 8 MB  [4096][1024]
    u16* wq_bf  = (u16*)(ws + 8 * MB);        // 2 MB
    u16* wk_bf  = (u16*)(ws + 10 * MB);       // 2 MB
    u16* wv_bf  = (u16*)(ws + 12 * MB);       // 2 MB
    u16* wo_bf  = (u16*)(ws + 14 * MB);       // 2 MB
    u16* q_bf   = (u16*)(ws + 16 * MB);       // 8 MB  [4096][1024]
    u16* k_bf   = (u16*)(ws + 24 * MB);       // 8 MB  [4096][1024]
    u16* vt_bf  = (u16*)(ws + 32 * MB);       // 8 MB  [1024][4096] (transposed)
    u16* at_bf  = (u16*)(ws + 40 * MB);       // 8 MB  [4096][1024]

    // casts
    cast_f32_bf16<<<dim3((MM * CC / 4) / 256), dim3(256), 0, stream>>>(
        (const float4*)x, (ushort4*)x_bf, MM * CC / 4);
    cast_f32_bf16<<<dim3((CC * CC / 4) / 256), dim3(256), 0, stream>>>(
        (const float4*)Wq, (ushort4*)wq_bf, CC * CC / 4);
    cast_f32_bf16<<<dim3((CC * CC / 4) / 256), dim3(256), 0, stream>>>(
        (const float4*)Wk, (ushort4*)wk_bf, CC * CC / 4);
    cast_f32_bf16<<<dim3((CC * CC / 4) / 256), dim3(256), 0, stream>>>(
        (const float4*)Wv, (ushort4*)wv_bf, CC * CC / 4);
    cast_f32_bf16<<<dim3((CC * CC / 4) / 256), dim3(256), 0, stream>>>(
        (const float4*)Wo, (ushort4*)wo_bf, CC * CC / 4);

    // projections: 4096 waves = 1024 blocks each
    dim3 ggrid(1024), gblk(256);
    gemm_bt<0><<<ggrid, gblk, 0, stream>>>(x_bf, wq_bf, q_bf, 0.125f, nullptr);
    gemm_bt<0><<<ggrid, gblk, 0, stream>>>(x_bf, wk_bf, k_bf, 1.0f, nullptr);
    gemm_bt<1><<<ggrid, gblk, 0, stream>>>(x_bf, wv_bf, vt_bf, 1.0f, nullptr);

    // attention: B*H*(T/16) = 4096 waves = 1024 blocks
    attn_fwd<<<dim3(1024), dim3(256), 0, stream>>>(q_bf, k_bf, vt_bf, at_bf);

    // output projection + bias -> fp32 d_out
    gemm_bt<2><<<ggrid, gblk, 0, stream>>>(at_bf, wo_bf, d_out, 1.0f, bo);
}

// Round 2
// 347.204 us; speedup vs baseline: 1.5502x; 1.5502x over previous
//
#include <hip/hip_runtime.h>

// Problem constants: B=2, T=2048, C=1024, H=16, S=64
#define BB 2
#define TT 2048
#define CC 1024
#define HH 16
#define SS 64
#define MM (BB * TT)   // 4096

typedef unsigned short u16;
typedef __bf16 bf16x8 __attribute__((ext_vector_type(8)));
typedef float f32x4 __attribute__((ext_vector_type(4)));

#define MFMA16(a, b, c) __builtin_amdgcn_mfma_f32_16x16x32_bf16((a), (b), (c), 0, 0, 0)

__device__ inline u16 f2bf(float f) {
    union { float f; unsigned u; } v;
    v.f = f;
    unsigned r = v.u + 0x7FFFu + ((v.u >> 16) & 1u);
    return (u16)(r >> 16);
}

// ---------------------------------------------------------------- fused casts
// x: 4096 blocks (4M elems). Each W: 1024 blocks (1M elems). Total 8192 blocks.
__global__ __launch_bounds__(256) void cast_all(
    const float4* __restrict__ x,  const float4* __restrict__ wq,
    const float4* __restrict__ wk, const float4* __restrict__ wv,
    const float4* __restrict__ wo,
    ushort4* __restrict__ xo, ushort4* __restrict__ qo,
    ushort4* __restrict__ ko, ushort4* __restrict__ vo,
    ushort4* __restrict__ oo) {
    int bid = blockIdx.x;
    const float4* src; ushort4* dst; int i;
    if (bid < 4096) {
        src = x; dst = xo; i = bid * 256 + threadIdx.x;
    } else {
        int s = (bid - 4096) >> 10;
        int r = (bid - 4096) & 1023;
        src = (s == 0) ? wq : (s == 1) ? wk : (s == 2) ? wv : wo;
        dst = (s == 0) ? qo : (s == 1) ? ko : (s == 2) ? vo : oo;
        i = r * 256 + threadIdx.x;
    }
    float4 v = src[i];
    ushort4 o;
    o.x = f2bf(v.x); o.y = f2bf(v.y); o.z = f2bf(v.z); o.w = f2bf(v.w);
    dst[i] = o;
}

// ---------------------------------------------------------------- 128x128 GEMM core
// C = A[MM][CC] * Bt[N][CC]^T, tile 128x128, BK=32, 4 waves (each a 64x64 quadrant).
// LDS tiles [128][32] bf16, linear dest for global_load_lds; source pre-swizzled
// (chunk ^= row&3) so ds_read_b128 fragment reads are ~2-way-conflict.
__device__ __forceinline__ void stage_tile(const u16* __restrict__ g, int row0, int k0,
                                           u16* lds) {
    int t = threadIdx.x;
#pragma unroll
    for (int q = 0; q < 2; ++q) {
        int idx = q * 256 + t;            // 16B chunk index, 0..511
        int row = idx >> 2;               // 0..127
        int chunk = (idx & 3) ^ (row & 3);  // pre-swizzled source chunk
        const u16* src = g + (long)(row0 + row) * CC + k0 + chunk * 8;
        __builtin_amdgcn_global_load_lds(
            (const __attribute__((address_space(1))) void*)src,
            (__attribute__((address_space(3))) void*)(lds + idx * 8), 16, 0, 0);
    }
}

__device__ __forceinline__ void gemm_core(const u16* __restrict__ A,
                                          const u16* __restrict__ Bt,
                                          int blkM, int blkN,
                                          u16* sA0, u16* sB0, u16* sA1, u16* sB1,
                                          f32x4 (&acc)[4][4]) {
    int lane = threadIdx.x & 63;
    int w = threadIdx.x >> 6;
    int wr = w >> 1, wc = w & 1;
    int l15 = lane & 15;
    int hi = lane >> 4;

#pragma unroll
    for (int m = 0; m < 4; ++m)
#pragma unroll
        for (int n = 0; n < 4; ++n) acc[m][n] = (f32x4){0.f, 0.f, 0.f, 0.f};

    stage_tile(A, blkM * 128, 0, sA0);
    stage_tile(Bt, blkN * 128, 0, sB0);

    for (int kt = 0; kt < CC / 32; ++kt) {
        __syncthreads();   // drains vmcnt -> current buffers ready; fences prev reads
        u16* cA = (kt & 1) ? sA1 : sA0;
        u16* cB = (kt & 1) ? sB1 : sB0;
        if (kt + 1 < CC / 32) {
            u16* nA = (kt & 1) ? sA0 : sA1;
            u16* nB = (kt & 1) ? sB0 : sB1;
            stage_tile(A, blkM * 128, (kt + 1) * 32, nA);
            stage_tile(Bt, blkN * 128, (kt + 1) * 32, nB);
        }
        bf16x8 af[4], bfr[4];
#pragma unroll
        for (int m = 0; m < 4; ++m) {
            int row = wr * 64 + m * 16 + l15;
            af[m] = *(const bf16x8*)(cA + row * 32 + ((hi ^ (row & 3)) << 3));
        }
#pragma unroll
        for (int n = 0; n < 4; ++n) {
            int row = wc * 64 + n * 16 + l15;
            bfr[n] = *(const bf16x8*)(cB + row * 32 + ((hi ^ (row & 3)) << 3));
        }
#pragma unroll
        for (int m = 0; m < 4; ++m)
#pragma unroll
            for (int n = 0; n < 4; ++n)
                acc[m][n] = MFMA16(af[m], bfr[n], acc[m][n]);
    }
}

// Fused QKV projection: grid = 3*256 blocks. seg 0=Q(scaled) 1=K 2=V(transposed).
__global__ __launch_bounds__(256) void qkv_gemm(const u16* __restrict__ xb,
                                                const u16* __restrict__ wqb,
                                                const u16* __restrict__ wkb,
                                                const u16* __restrict__ wvb,
                                                u16* __restrict__ qo,
                                                u16* __restrict__ ko,
                                                u16* __restrict__ vt) {
    __shared__ u16 smem[4][128 * 32];
    int seg = blockIdx.x >> 8;
    int bid = blockIdx.x & 255;
    int blkM = bid & 31, blkN = bid >> 5;
    const u16* Bt = (seg == 0) ? wqb : (seg == 1) ? wkb : wvb;
    f32x4 acc[4][4];
    gemm_core(xb, Bt, blkM, blkN, smem[0], smem[1], smem[2], smem[3], acc);

    int lane = threadIdx.x & 63;
    int w = threadIdx.x >> 6, wr = w >> 1, wc = w & 1;
    int l15 = lane & 15, hi = lane >> 4;
    int r0 = blkM * 128 + wr * 64 + hi * 4;
    int c0 = blkN * 128 + wc * 64 + l15;

    if (seg == 2) {  // V transposed: vt[c][r], 4 consecutive rows -> ushort4
#pragma unroll
        for (int m = 0; m < 4; ++m)
#pragma unroll
            for (int n = 0; n < 4; ++n) {
                ushort4 p;
                p.x = f2bf(acc[m][n][0]); p.y = f2bf(acc[m][n][1]);
                p.z = f2bf(acc[m][n][2]); p.w = f2bf(acc[m][n][3]);
                *(ushort4*)(vt + (long)(c0 + n * 16) * MM + r0 + m * 16) = p;
            }
    } else {
        u16* dst = (seg == 0) ? qo : ko;
        float sc = (seg == 0) ? 0.125f : 1.0f;
#pragma unroll
        for (int m = 0; m < 4; ++m)
#pragma unroll
            for (int n = 0; n < 4; ++n)
#pragma unroll
                for (int i = 0; i < 4; ++i)
                    dst[(long)(r0 + m * 16 + i) * CC + c0 + n * 16] =
                        f2bf(acc[m][n][i] * sc);
    }
}

// Output projection: f32 + bias into d_out. grid = 256 blocks.
__global__ __launch_bounds__(256) void out_gemm(const u16* __restrict__ at,
                                                const u16* __restrict__ wob,
                                                const float* __restrict__ bias,
                                                float* __restrict__ out) {
    __shared__ u16 smem[4][128 * 32];
    int bid = blockIdx.x;
    int blkM = bid & 31, blkN = bid >> 5;
    f32x4 acc[4][4];
    gemm_core(at, wob, blkM, blkN, smem[0], smem[1], smem[2], smem[3], acc);

    int lane = threadIdx.x & 63;
    int w = threadIdx.x >> 6, wr = w >> 1, wc = w & 1;
    int l15 = lane & 15, hi = lane >> 4;
    int r0 = blkM * 128 + wr * 64 + hi * 4;
    int c0 = blkN * 128 + wc * 64 + l15;
#pragma unroll
    for (int n = 0; n < 4; ++n) {
        int c = c0 + n * 16;
        float bv = bias[c];
#pragma unroll
        for (int m = 0; m < 4; ++m)
#pragma unroll
            for (int i = 0; i < 4; ++i)
                out[(long)(r0 + m * 16 + i) * CC + c] = acc[m][n][i] + bv;
    }
}

// ---------------------------------------------------------------- flash attention
// KVBLK=64. One wave = 16 q-rows of one (b,h). Q pre-scaled. Vt transposed.
__global__ __launch_bounds__(256) void attn_fwd(const u16* __restrict__ Q,
                                                const u16* __restrict__ Kb,
                                                const u16* __restrict__ Vt,
                                                u16* __restrict__ O) {
    __shared__ u16 Plds[4][16 * 64];
    int lane = threadIdx.x & 63;
    int wloc = threadIdx.x >> 6;
    int wave = blockIdx.x * 4 + wloc;
    int qt = wave & 127;
    int bh = wave >> 7;
    int h = bh & 15;
    int b = bh >> 4;
    int q0 = qt << 4;
    int l15 = lane & 15;
    int hi = lane >> 4;
    int ko = hi << 3;

    const long rowQ = (long)(b * TT + q0 + l15) * CC + h * SS;
    bf16x8 qf0 = *(const bf16x8*)(Q + rowQ + ko);
    bf16x8 qf1 = *(const bf16x8*)(Q + rowQ + 32 + ko);

    f32x4 oa[4];
    float mr[4], lr[4];
#pragma unroll
    for (int j = 0; j < 4; ++j) oa[j] = (f32x4){0.f, 0.f, 0.f, 0.f};
#pragma unroll
    for (int i = 0; i < 4; ++i) { mr[i] = -1e30f; lr[i] = 0.f; }

    u16* P = Plds[wloc];
    int nblk = (q0 + 79) >> 6;   // ceil((q0+16)/64)

    for (int blk = 0; blk < nblk; ++blk) {
        int kv0 = blk << 6;
        f32x4 s[4];
#pragma unroll
        for (int jj = 0; jj < 4; ++jj) s[jj] = (f32x4){0.f, 0.f, 0.f, 0.f};

        const u16* Kbase = Kb + (long)(b * TT + kv0 + l15) * CC + h * SS + ko;
#pragma unroll
        for (int jj = 0; jj < 4; ++jj) {
            bf16x8 k0 = *(const bf16x8*)(Kbase + (long)jj * 16 * CC);
            bf16x8 k1 = *(const bf16x8*)(Kbase + (long)jj * 16 * CC + 32);
            s[jj] = MFMA16(qf0, k0, s[jj]);
            s[jj] = MFMA16(qf1, k1, s[jj]);
        }

        if (kv0 + 63 > q0) {  // causal mask
            int qrow = q0 + (hi << 2);
#pragma unroll
            for (int jj = 0; jj < 4; ++jj) {
                int kc = kv0 + jj * 16 + l15;
#pragma unroll
                for (int i = 0; i < 4; ++i)
                    if (kc > qrow + i) s[jj][i] = -1e30f;
            }
        }

#pragma unroll
        for (int i = 0; i < 4; ++i) {
            float mx = fmaxf(fmaxf(s[0][i], s[1][i]), fmaxf(s[2][i], s[3][i]));
            mx = fmaxf(mx, __shfl_xor(mx, 1));
            mx = fmaxf(mx, __shfl_xor(mx, 2));
            mx = fmaxf(mx, __shfl_xor(mx, 4));
            mx = fmaxf(mx, __shfl_xor(mx, 8));
            float mnew = fmaxf(mr[i], mx);
            float scl = __expf(mr[i] - mnew);
            float p0 = __expf(s[0][i] - mnew);
            float p1 = __expf(s[1][i] - mnew);
            float p2 = __expf(s[2][i] - mnew);
            float p3 = __expf(s[3][i] - mnew);
            float rs = (p0 + p1) + (p2 + p3);
            rs += __shfl_xor(rs, 1);
            rs += __shfl_xor(rs, 2);
            rs += __shfl_xor(rs, 4);
            rs += __shfl_xor(rs, 8);
            lr[i] = lr[i] * scl + rs;
            mr[i] = mnew;
            oa[0][i] *= scl; oa[1][i] *= scl; oa[2][i] *= scl; oa[3][i] *= scl;
            int prow = (hi << 2) + i;
            P[prow * 64 + l15]      = f2bf(p0);
            P[prow * 64 + 16 + l15] = f2bf(p1);
            P[prow * 64 + 32 + l15] = f2bf(p2);
            P[prow * 64 + 48 + l15] = f2bf(p3);
        }
        asm volatile("s_waitcnt lgkmcnt(0)" ::: "memory");

        bf16x8 pf0 = *(const bf16x8*)(P + l15 * 64 + ko);
        bf16x8 pf1 = *(const bf16x8*)(P + l15 * 64 + 32 + ko);
        const long vbase = (long)(h * SS + l15) * MM + b * TT + kv0 + ko;
#pragma unroll
        for (int j = 0; j < 4; ++j) {
            bf16x8 v0 = *(const bf16x8*)(Vt + vbase + (long)j * 16 * MM);
            bf16x8 v1 = *(const bf16x8*)(Vt + vbase + (long)j * 16 * MM + 32);
            oa[j] = MFMA16(pf0, v0, oa[j]);
            oa[j] = MFMA16(pf1, v1, oa[j]);
        }
    }

#pragma unroll
    for (int i = 0; i < 4; ++i) {
        float inv = 1.0f / lr[i];
        int trow = q0 + (hi << 2) + i;
        long obase = (long)(b * TT + trow) * CC + h * SS + l15;
        O[obase + 0]  = f2bf(oa[0][i] * inv);
        O[obase + 16] = f2bf(oa[1][i] * inv);
        O[obase + 32] = f2bf(oa[2][i] * inv);
        O[obase + 48] = f2bf(oa[3][i] * inv);
    }
}

// ---------------------------------------------------------------- launch
extern "C" void kernel_launch(void* const* d_in, const int* in_sizes, int n_in,
                              void* d_out, int out_size, void* d_ws, size_t ws_size,
                              hipStream_t stream) {
    const float* x  = (const float*)d_in[0];
    const float* Wq = (const float*)d_in[1];
    const float* Wk = (const float*)d_in[2];
    const float* Wv = (const float*)d_in[3];
    const float* Wo = (const float*)d_in[4];
    const float* bo = (const float*)d_in[5];

    char* ws = (char*)d_ws;
    const size_t MB = 1024 * 1024;
    u16* x_bf  = (u16*)(ws);             // 8 MB [4096][1024]
    u16* wq_bf = (u16*)(ws + 8 * MB);    // 2 MB
    u16* wk_bf = (u16*)(ws + 10 * MB);   // 2 MB
    u16* wv_bf = (u16*)(ws + 12 * MB);   // 2 MB
    u16* wo_bf = (u16*)(ws + 14 * MB);   // 2 MB
    u16* q_bf  = (u16*)(ws + 16 * MB);   // 8 MB [4096][1024]
    u16* k_bf  = (u16*)(ws + 24 * MB);   // 8 MB [4096][1024]
    u16* vt_bf = (u16*)(ws + 32 * MB);   // 8 MB [1024][4096] transposed
    u16* at_bf = (u16*)(ws + 40 * MB);   // 8 MB [4096][1024]

    cast_all<<<dim3(8192), dim3(256), 0, stream>>>(
        (const float4*)x, (const float4*)Wq, (const float4*)Wk,
        (const float4*)Wv, (const float4*)Wo,
        (ushort4*)x_bf, (ushort4*)wq_bf, (ushort4*)wk_bf,
        (ushort4*)wv_bf, (ushort4*)wo_bf);

    qkv_gemm<<<dim3(768), dim3(256), 0, stream>>>(x_bf, wq_bf, wk_bf, wv_bf,
                                                  q_bf, k_bf, vt_bf);

    attn_fwd<<<dim3(1024), dim3(256), 0, stream>>>(q_bf, k_bf, vt_bf, at_bf);

    out_gemm<<<dim3(256), dim3(256), 0, stream>>>(at_bf, wo_bf, bo, (float*)d_out);
}

// Round 3
// 139.260 us; speedup vs baseline: 3.8649x; 2.4932x over previous
//
#include <hip/hip_runtime.h>

// Problem constants: B=2, T=2048, C=1024, H=16, S=64
#define BB 2
#define TT 2048
#define CC 1024
#define HH 16
#define SS 64
#define MM (BB * TT)   // 4096

typedef unsigned short u16;
typedef __bf16 bf16x8 __attribute__((ext_vector_type(8)));
typedef float f32x4 __attribute__((ext_vector_type(4)));

#define MFMA16(a, b, c) __builtin_amdgcn_mfma_f32_16x16x32_bf16((a), (b), (c), 0, 0, 0)

__device__ inline u16 f2bf(float f) {
    union { float f; unsigned u; } v;
    v.f = f;
    unsigned r = v.u + 0x7FFFu + ((v.u >> 16) & 1u);
    return (u16)(r >> 16);
}

// ---------------------------------------------------------------- fused casts
__global__ __launch_bounds__(256) void cast_all(
    const float4* __restrict__ x,  const float4* __restrict__ wq,
    const float4* __restrict__ wk, const float4* __restrict__ wv,
    const float4* __restrict__ wo,
    ushort4* __restrict__ xo, ushort4* __restrict__ qo,
    ushort4* __restrict__ ko, ushort4* __restrict__ vo,
    ushort4* __restrict__ oo) {
    int bid = blockIdx.x;
    const float4* src; ushort4* dst; int i;
    if (bid < 4096) {
        src = x; dst = xo; i = bid * 256 + threadIdx.x;
    } else {
        int s = (bid - 4096) >> 10;
        int r = (bid - 4096) & 1023;
        src = (s == 0) ? wq : (s == 1) ? wk : (s == 2) ? wv : wo;
        dst = (s == 0) ? qo : (s == 1) ? ko : (s == 2) ? vo : oo;
        i = r * 256 + threadIdx.x;
    }
    float4 v = src[i];
    ushort4 o;
    o.x = f2bf(v.x); o.y = f2bf(v.y); o.z = f2bf(v.z); o.w = f2bf(v.w);
    dst[i] = o;
}

// ---------------------------------------------------------------- 128x128 GEMM core
__device__ __forceinline__ void stage_tile(const u16* __restrict__ g, int row0, int k0,
                                           u16* lds) {
    int t = threadIdx.x;
#pragma unroll
    for (int q = 0; q < 2; ++q) {
        int idx = q * 256 + t;
        int row = idx >> 2;
        int chunk = (idx & 3) ^ (row & 3);
        const u16* src = g + (long)(row0 + row) * CC + k0 + chunk * 8;
        __builtin_amdgcn_global_load_lds(
            (const __attribute__((address_space(1))) void*)src,
            (__attribute__((address_space(3))) void*)(lds + idx * 8), 16, 0, 0);
    }
}

__device__ __forceinline__ void gemm_core(const u16* __restrict__ A,
                                          const u16* __restrict__ Bt,
                                          int blkM, int blkN,
                                          u16* sA0, u16* sB0, u16* sA1, u16* sB1,
                                          f32x4 (&acc)[4][4]) {
    int lane = threadIdx.x & 63;
    int w = threadIdx.x >> 6;
    int wr = w >> 1, wc = w & 1;
    int l15 = lane & 15;
    int hi = lane >> 4;

#pragma unroll
    for (int m = 0; m < 4; ++m)
#pragma unroll
        for (int n = 0; n < 4; ++n) acc[m][n] = (f32x4){0.f, 0.f, 0.f, 0.f};

    stage_tile(A, blkM * 128, 0, sA0);
    stage_tile(Bt, blkN * 128, 0, sB0);

    for (int kt = 0; kt < CC / 32; ++kt) {
        __syncthreads();
        u16* cA = (kt & 1) ? sA1 : sA0;
        u16* cB = (kt & 1) ? sB1 : sB0;
        if (kt + 1 < CC / 32) {
            u16* nA = (kt & 1) ? sA0 : sA1;
            u16* nB = (kt & 1) ? sB0 : sB1;
            stage_tile(A, blkM * 128, (kt + 1) * 32, nA);
            stage_tile(Bt, blkN * 128, (kt + 1) * 32, nB);
        }
        bf16x8 af[4], bfr[4];
#pragma unroll
        for (int m = 0; m < 4; ++m) {
            int row = wr * 64 + m * 16 + l15;
            af[m] = *(const bf16x8*)(cA + row * 32 + ((hi ^ (row & 3)) << 3));
        }
#pragma unroll
        for (int n = 0; n < 4; ++n) {
            int row = wc * 64 + n * 16 + l15;
            bfr[n] = *(const bf16x8*)(cB + row * 32 + ((hi ^ (row & 3)) << 3));
        }
#pragma unroll
        for (int m = 0; m < 4; ++m)
#pragma unroll
            for (int n = 0; n < 4; ++n)
                acc[m][n] = MFMA16(af[m], bfr[n], acc[m][n]);
    }
}

__global__ __launch_bounds__(256) void qkv_gemm(const u16* __restrict__ xb,
                                                const u16* __restrict__ wqb,
                                                const u16* __restrict__ wkb,
                                                const u16* __restrict__ wvb,
                                                u16* __restrict__ qo,
                                                u16* __restrict__ ko,
                                                u16* __restrict__ vt) {
    __shared__ u16 smem[4][128 * 32];
    int seg = blockIdx.x >> 8;
    int bid = blockIdx.x & 255;
    int blkM = bid & 31, blkN = bid >> 5;
    const u16* Bt = (seg == 0) ? wqb : (seg == 1) ? wkb : wvb;
    f32x4 acc[4][4];
    gemm_core(xb, Bt, blkM, blkN, smem[0], smem[1], smem[2], smem[3], acc);

    int lane = threadIdx.x & 63;
    int w = threadIdx.x >> 6, wr = w >> 1, wc = w & 1;
    int l15 = lane & 15, hi = lane >> 4;
    int r0 = blkM * 128 + wr * 64 + hi * 4;
    int c0 = blkN * 128 + wc * 64 + l15;

    if (seg == 2) {
#pragma unroll
        for (int m = 0; m < 4; ++m)
#pragma unroll
            for (int n = 0; n < 4; ++n) {
                ushort4 p;
                p.x = f2bf(acc[m][n][0]); p.y = f2bf(acc[m][n][1]);
                p.z = f2bf(acc[m][n][2]); p.w = f2bf(acc[m][n][3]);
                *(ushort4*)(vt + (long)(c0 + n * 16) * MM + r0 + m * 16) = p;
            }
    } else {
        u16* dst = (seg == 0) ? qo : ko;
        float sc = (seg == 0) ? 0.125f : 1.0f;
#pragma unroll
        for (int m = 0; m < 4; ++m)
#pragma unroll
            for (int n = 0; n < 4; ++n)
#pragma unroll
                for (int i = 0; i < 4; ++i)
                    dst[(long)(r0 + m * 16 + i) * CC + c0 + n * 16] =
                        f2bf(acc[m][n][i] * sc);
    }
}

__global__ __launch_bounds__(256) void out_gemm(const u16* __restrict__ at,
                                                const u16* __restrict__ wob,
                                                const float* __restrict__ bias,
                                                float* __restrict__ out) {
    __shared__ u16 smem[4][128 * 32];
    int bid = blockIdx.x;
    int blkM = bid & 31, blkN = bid >> 5;
    f32x4 acc[4][4];
    gemm_core(at, wob, blkM, blkN, smem[0], smem[1], smem[2], smem[3], acc);

    int lane = threadIdx.x & 63;
    int w = threadIdx.x >> 6, wr = w >> 1, wc = w & 1;
    int l15 = lane & 15, hi = lane >> 4;
    int r0 = blkM * 128 + wr * 64 + hi * 4;
    int c0 = blkN * 128 + wc * 64 + l15;
#pragma unroll
    for (int n = 0; n < 4; ++n) {
        int c = c0 + n * 16;
        float bv = bias[c];
#pragma unroll
        for (int m = 0; m < 4; ++m)
#pragma unroll
            for (int i = 0; i < 4; ++i)
                out[(long)(r0 + m * 16 + i) * CC + c] = acc[m][n][i] + bv;
    }
}

// ---------------------------------------------------------------- flash attention v3
// Block = 4 waves = one (b,h), 64 q-rows (16/wave). KV tiles of 64, K+V staged in
// LDS (double-buffered, XOR-swizzled source). Causal pairing: block does q-tiles
// (pair) and (31-pair) -> constant 33 KV tiles/block.
__device__ __forceinline__ void stage_kv(const u16* __restrict__ Kg,
                                         const u16* __restrict__ Vg,
                                         u16* dK, u16* dV) {
    int t = threadIdx.x;
#pragma unroll
    for (int q = 0; q < 2; ++q) {
        int c = q * 256 + t;           // 16B chunk 0..511
        int row = c >> 3, col = c & 7;
        int scol = col ^ (row & 7);    // pre-swizzled source chunk
        __builtin_amdgcn_global_load_lds(
            (const __attribute__((address_space(1))) void*)(Kg + (long)row * CC + scol * 8),
            (__attribute__((address_space(3))) void*)(dK + c * 8), 16, 0, 0);
        __builtin_amdgcn_global_load_lds(
            (const __attribute__((address_space(1))) void*)(Vg + (long)row * MM + scol * 8),
            (__attribute__((address_space(3))) void*)(dV + c * 8), 16, 0, 0);
    }
}

__global__ __launch_bounds__(256) void attn_fwd(const u16* __restrict__ Q,
                                                const u16* __restrict__ Kb,
                                                const u16* __restrict__ Vt,
                                                u16* __restrict__ O) {
    __shared__ u16 sK[2][64 * 64];
    __shared__ u16 sV[2][64 * 64];
    __shared__ u16 sP[4][16 * 72];   // stride 72 (144B, 16B-aligned, conflict-lite)
    int lane = threadIdx.x & 63;
    int wloc = threadIdx.x >> 6;
    int bh = blockIdx.x >> 4;        // 0..31
    int pair = blockIdx.x & 15;      // 0..15
    int h = bh & 15, b = bh >> 4;
    int l15 = lane & 15, hi = lane >> 4, ko = hi << 3;
    u16* P = sP[wloc];

#pragma unroll 1
    for (int pass = 0; pass < 2; ++pass) {
        int qt = pass ? (31 - pair) : pair;   // q-tile of 64 rows
        int q0 = qt * 64 + wloc * 16;
        const long rowQ = (long)(b * TT + q0 + l15) * CC + h * SS;
        bf16x8 qf0 = *(const bf16x8*)(Q + rowQ + ko);
        bf16x8 qf1 = *(const bf16x8*)(Q + rowQ + 32 + ko);

        f32x4 oa[4];
        float mr[4], lr[4];
#pragma unroll
        for (int j = 0; j < 4; ++j) oa[j] = (f32x4){0.f, 0.f, 0.f, 0.f};
#pragma unroll
        for (int i = 0; i < 4; ++i) { mr[i] = -1e30f; lr[i] = 0.f; }

        int ntiles = qt + 1;
        const u16* Kgb = Kb + (long)(b * TT) * CC + h * SS;
        const u16* Vgb = Vt + (long)(h * SS) * MM + b * TT;

        __syncthreads();  // previous pass's reads done before restaging buf0
        stage_kv(Kgb, Vgb, sK[0], sV[0]);

#pragma unroll 1
        for (int t = 0; t < ntiles; ++t) {
            __syncthreads();  // drains vmcnt -> buf[t&1] ready; fences prev reads
            const u16* cK = sK[t & 1];
            const u16* cV = sV[t & 1];
            if (t + 1 < ntiles)
                stage_kv(Kgb + (long)(t + 1) * 64 * CC, Vgb + (t + 1) * 64,
                         sK[(t + 1) & 1], sV[(t + 1) & 1]);

            int kv0 = t << 6;
            f32x4 s[4];
#pragma unroll
            for (int jj = 0; jj < 4; ++jj) s[jj] = (f32x4){0.f, 0.f, 0.f, 0.f};
#pragma unroll
            for (int jj = 0; jj < 4; ++jj) {
                int r = jj * 16 + l15;
                bf16x8 k0 = *(const bf16x8*)(cK + r * 64 + ((hi ^ (r & 7)) << 3));
                bf16x8 k1 = *(const bf16x8*)(cK + r * 64 + (((4 + hi) ^ (r & 7)) << 3));
                s[jj] = MFMA16(qf0, k0, s[jj]);
                s[jj] = MFMA16(qf1, k1, s[jj]);
            }

            if (t == qt) {  // diagonal tile: causal mask
                int qrow = q0 + (hi << 2);
#pragma unroll
                for (int jj = 0; jj < 4; ++jj) {
                    int kc = kv0 + jj * 16 + l15;
#pragma unroll
                    for (int i = 0; i < 4; ++i)
                        if (kc > qrow + i) s[jj][i] = -1e30f;
                }
            }

#pragma unroll
            for (int i = 0; i < 4; ++i) {
                float mx = fmaxf(fmaxf(s[0][i], s[1][i]), fmaxf(s[2][i], s[3][i]));
                mx = fmaxf(mx, __shfl_xor(mx, 1));
                mx = fmaxf(mx, __shfl_xor(mx, 2));
                mx = fmaxf(mx, __shfl_xor(mx, 4));
                mx = fmaxf(mx, __shfl_xor(mx, 8));
                float mnew = fmaxf(mr[i], mx);
                float scl = __expf(mr[i] - mnew);
                float p0 = __expf(s[0][i] - mnew);
                float p1 = __expf(s[1][i] - mnew);
                float p2 = __expf(s[2][i] - mnew);
                float p3 = __expf(s[3][i] - mnew);
                float rs = (p0 + p1) + (p2 + p3);
                rs += __shfl_xor(rs, 1);
                rs += __shfl_xor(rs, 2);
                rs += __shfl_xor(rs, 4);
                rs += __shfl_xor(rs, 8);
                lr[i] = lr[i] * scl + rs;
                mr[i] = mnew;
                oa[0][i] *= scl; oa[1][i] *= scl; oa[2][i] *= scl; oa[3][i] *= scl;
                int prow = (hi << 2) + i;
                P[prow * 72 + l15]      = f2bf(p0);
                P[prow * 72 + 16 + l15] = f2bf(p1);
                P[prow * 72 + 32 + l15] = f2bf(p2);
                P[prow * 72 + 48 + l15] = f2bf(p3);
            }
            asm volatile("s_waitcnt lgkmcnt(0)" ::: "memory");

            bf16x8 pf0 = *(const bf16x8*)(P + l15 * 72 + ko);
            bf16x8 pf1 = *(const bf16x8*)(P + l15 * 72 + 32 + ko);
#pragma unroll
            for (int j = 0; j < 4; ++j) {
                int r = j * 16 + l15;
                bf16x8 v0 = *(const bf16x8*)(cV + r * 64 + ((hi ^ (r & 7)) << 3));
                bf16x8 v1 = *(const bf16x8*)(cV + r * 64 + (((4 + hi) ^ (r & 7)) << 3));
                oa[j] = MFMA16(pf0, v0, oa[j]);
                oa[j] = MFMA16(pf1, v1, oa[j]);
            }
        }

#pragma unroll
        for (int i = 0; i < 4; ++i) {
            float inv = 1.0f / lr[i];
            int trow = q0 + (hi << 2) + i;
            long obase = (long)(b * TT + trow) * CC + h * SS + l15;
            O[obase + 0]  = f2bf(oa[0][i] * inv);
            O[obase + 16] = f2bf(oa[1][i] * inv);
            O[obase + 32] = f2bf(oa[2][i] * inv);
            O[obase + 48] = f2bf(oa[3][i] * inv);
        }
    }
}

// ---------------------------------------------------------------- launch
extern "C" void kernel_launch(void* const* d_in, const int* in_sizes, int n_in,
                              void* d_out, int out_size, void* d_ws, size_t ws_size,
                              hipStream_t stream) {
    const float* x  = (const float*)d_in[0];
    const float* Wq = (const float*)d_in[1];
    const float* Wk = (const float*)d_in[2];
    const float* Wv = (const float*)d_in[3];
    const float* Wo = (const float*)d_in[4];
    const float* bo = (const float*)d_in[5];

    char* ws = (char*)d_ws;
    const size_t MB = 1024 * 1024;
    u16* x_bf  = (u16*)(ws);
    u16* wq_bf = (u16*)(ws + 8 * MB);
    u16* wk_bf = (u16*)(ws + 10 * MB);
    u16* wv_bf = (u16*)(ws + 12 * MB);
    u16* wo_bf = (u16*)(ws + 14 * MB);
    u16* q_bf  = (u16*)(ws + 16 * MB);
    u16* k_bf  = (u16*)(ws + 24 * MB);
    u16* vt_bf = (u16*)(ws + 32 * MB);   // [1024][4096] transposed
    u16* at_bf = (u16*)(ws + 40 * MB);

    cast_all<<<dim3(8192), dim3(256), 0, stream>>>(
        (const float4*)x, (const float4*)Wq, (const float4*)Wk,
        (const float4*)Wv, (const float4*)Wo,
        (ushort4*)x_bf, (ushort4*)wq_bf, (ushort4*)wk_bf,
        (ushort4*)wv_bf, (ushort4*)wo_bf);

    qkv_gemm<<<dim3(768), dim3(256), 0, stream>>>(x_bf, wq_bf, wk_bf, wv_bf,
                                                  q_bf, k_bf, vt_bf);

    attn_fwd<<<dim3(512), dim3(256), 0, stream>>>(q_bf, k_bf, vt_bf, at_bf);

    out_gemm<<<dim3(256), dim3(256), 0, stream>>>(at_bf, wo_bf, bo, (float*)d_out);
}

// Round 5
// 128.549 us; speedup vs baseline: 4.1870x; 1.0833x over previous
//
#include <hip/hip_runtime.h>

// Problem constants: B=2, T=2048, C=1024, H=16, S=64
#define BB 2
#define TT 2048
#define CC 1024
#define HH 16
#define SS 64
#define MM (BB * TT)   // 4096

typedef unsigned short u16;
typedef __bf16 bf16x8 __attribute__((ext_vector_type(8)));
typedef float f32x4 __attribute__((ext_vector_type(4)));
typedef float f32x16 __attribute__((ext_vector_type(16)));

#define MFMA16(a, b, c) __builtin_amdgcn_mfma_f32_16x16x32_bf16((a), (b), (c), 0, 0, 0)
#define MFMA32(a, b, c) __builtin_amdgcn_mfma_f32_32x32x16_bf16((a), (b), (c), 0, 0, 0)

__device__ inline u16 f2bf(float f) {
    union { float f; unsigned u; } v;
    v.f = f;
    unsigned r = v.u + 0x7FFFu + ((v.u >> 16) & 1u);
    return (u16)(r >> 16);
}

// ---------------------------------------------------------------- fused casts
__global__ __launch_bounds__(256) void cast_all(
    const float4* __restrict__ x,  const float4* __restrict__ wq,
    const float4* __restrict__ wk, const float4* __restrict__ wv,
    const float4* __restrict__ wo,
    ushort4* __restrict__ xo, ushort4* __restrict__ qo,
    ushort4* __restrict__ ko, ushort4* __restrict__ vo,
    ushort4* __restrict__ oo) {
    int bid = blockIdx.x;
    const float4* src; ushort4* dst; int i;
    if (bid < 4096) {
        src = x; dst = xo; i = bid * 256 + threadIdx.x;
    } else {
        int s = (bid - 4096) >> 10;
        int r = (bid - 4096) & 1023;
        src = (s == 0) ? wq : (s == 1) ? wk : (s == 2) ? wv : wo;
        dst = (s == 0) ? qo : (s == 1) ? ko : (s == 2) ? vo : oo;
        i = r * 256 + threadIdx.x;
    }
    float4 v = src[i];
    ushort4 o;
    o.x = f2bf(v.x); o.y = f2bf(v.y); o.z = f2bf(v.z); o.w = f2bf(v.w);
    dst[i] = o;
}

// ---------------------------------------------------------------- 128x128 GEMM core
__device__ __forceinline__ void stage_tile(const u16* __restrict__ g, int row0, int k0,
                                           u16* lds) {
    int t = threadIdx.x;
#pragma unroll
    for (int q = 0; q < 2; ++q) {
        int idx = q * 256 + t;
        int row = idx >> 2;
        int chunk = (idx & 3) ^ (row & 3);
        const u16* src = g + (long)(row0 + row) * CC + k0 + chunk * 8;
        __builtin_amdgcn_global_load_lds(
            (const __attribute__((address_space(1))) void*)src,
            (__attribute__((address_space(3))) void*)(lds + idx * 8), 16, 0, 0);
    }
}

__device__ __forceinline__ void gemm_core(const u16* __restrict__ A,
                                          const u16* __restrict__ Bt,
                                          int blkM, int blkN,
                                          u16* sA0, u16* sB0, u16* sA1, u16* sB1,
                                          f32x4 (&acc)[4][4]) {
    int lane = threadIdx.x & 63;
    int w = threadIdx.x >> 6;
    int wr = w >> 1, wc = w & 1;
    int l15 = lane & 15;
    int hi = lane >> 4;

#pragma unroll
    for (int m = 0; m < 4; ++m)
#pragma unroll
        for (int n = 0; n < 4; ++n) acc[m][n] = (f32x4){0.f, 0.f, 0.f, 0.f};

    stage_tile(A, blkM * 128, 0, sA0);
    stage_tile(Bt, blkN * 128, 0, sB0);

    for (int kt = 0; kt < CC / 32; ++kt) {
        __syncthreads();
        u16* cA = (kt & 1) ? sA1 : sA0;
        u16* cB = (kt & 1) ? sB1 : sB0;
        if (kt + 1 < CC / 32) {
            u16* nA = (kt & 1) ? sA0 : sA1;
            u16* nB = (kt & 1) ? sB0 : sB1;
            stage_tile(A, blkM * 128, (kt + 1) * 32, nA);
            stage_tile(Bt, blkN * 128, (kt + 1) * 32, nB);
        }
        bf16x8 af[4], bfr[4];
#pragma unroll
        for (int m = 0; m < 4; ++m) {
            int row = wr * 64 + m * 16 + l15;
            af[m] = *(const bf16x8*)(cA + row * 32 + ((hi ^ (row & 3)) << 3));
        }
#pragma unroll
        for (int n = 0; n < 4; ++n) {
            int row = wc * 64 + n * 16 + l15;
            bfr[n] = *(const bf16x8*)(cB + row * 32 + ((hi ^ (row & 3)) << 3));
        }
#pragma unroll
        for (int m = 0; m < 4; ++m)
#pragma unroll
            for (int n = 0; n < 4; ++n)
                acc[m][n] = MFMA16(af[m], bfr[n], acc[m][n]);
    }
}

__global__ __launch_bounds__(256) void qkv_gemm(const u16* __restrict__ xb,
                                                const u16* __restrict__ wqb,
                                                const u16* __restrict__ wkb,
                                                const u16* __restrict__ wvb,
                                                u16* __restrict__ qo,
                                                u16* __restrict__ ko,
                                                u16* __restrict__ vt) {
    __shared__ u16 smem[4][128 * 32];
    int seg = blockIdx.x >> 8;
    int bid = blockIdx.x & 255;
    int blkM = bid & 31, blkN = bid >> 5;
    const u16* Bt = (seg == 0) ? wqb : (seg == 1) ? wkb : wvb;
    f32x4 acc[4][4];
    gemm_core(xb, Bt, blkM, blkN, smem[0], smem[1], smem[2], smem[3], acc);

    int lane = threadIdx.x & 63;
    int w = threadIdx.x >> 6, wr = w >> 1, wc = w & 1;
    int l15 = lane & 15, hi = lane >> 4;
    int r0 = blkM * 128 + wr * 64 + hi * 4;
    int c0 = blkN * 128 + wc * 64 + l15;

    if (seg == 2) {
#pragma unroll
        for (int m = 0; m < 4; ++m)
#pragma unroll
            for (int n = 0; n < 4; ++n) {
                ushort4 p;
                p.x = f2bf(acc[m][n][0]); p.y = f2bf(acc[m][n][1]);
                p.z = f2bf(acc[m][n][2]); p.w = f2bf(acc[m][n][3]);
                *(ushort4*)(vt + (long)(c0 + n * 16) * MM + r0 + m * 16) = p;
            }
    } else {
        u16* dst = (seg == 0) ? qo : ko;
        float sc = (seg == 0) ? 0.125f : 1.0f;
#pragma unroll
        for (int m = 0; m < 4; ++m)
#pragma unroll
            for (int n = 0; n < 4; ++n)
#pragma unroll
                for (int i = 0; i < 4; ++i)
                    dst[(long)(r0 + m * 16 + i) * CC + c0 + n * 16] =
                        f2bf(acc[m][n][i] * sc);
    }
}

__global__ __launch_bounds__(256) void out_gemm(const u16* __restrict__ at,
                                                const u16* __restrict__ wob,
                                                const float* __restrict__ bias,
                                                float* __restrict__ out) {
    __shared__ u16 smem[4][128 * 32];
    int bid = blockIdx.x;
    int blkM = bid & 31, blkN = bid >> 5;
    f32x4 acc[4][4];
    gemm_core(at, wob, blkM, blkN, smem[0], smem[1], smem[2], smem[3], acc);

    int lane = threadIdx.x & 63;
    int w = threadIdx.x >> 6, wr = w >> 1, wc = w & 1;
    int l15 = lane & 15, hi = lane >> 4;
    int r0 = blkM * 128 + wr * 64 + hi * 4;
    int c0 = blkN * 128 + wc * 64 + l15;
#pragma unroll
    for (int n = 0; n < 4; ++n) {
        int c = c0 + n * 16;
        float bv = bias[c];
#pragma unroll
        for (int m = 0; m < 4; ++m)
#pragma unroll
            for (int i = 0; i < 4; ++i)
                out[(long)(r0 + m * 16 + i) * CC + c] = acc[m][n][i] + bv;
    }
}

// ---------------------------------------------------------------- flash attention v5
// Swapped QK^T with 32x32x16 MFMA; in-register softmax (lane owns a q column);
// P repack via per-wave LDS roundtrip (verified-layout mechanics only).
// Block = 2 waves, wave = 32 q-rows (qt = 2g+w). KV tiles of 64, LDS dbuf.
// Grid: bh = i&31 (same bh -> same XCD), g = 31 - (i>>5) (LPT).
__device__ __forceinline__ void stage_kv2(const u16* __restrict__ Kg,
                                          const u16* __restrict__ Vg,
                                          u16* dK, u16* dV) {
    int t = threadIdx.x;   // 0..127
#pragma unroll
    for (int q = 0; q < 4; ++q) {
        int c = q * 128 + t;           // 16B chunk 0..511
        int row = c >> 3, col = c & 7;
        int scol = col ^ (row & 7);
        __builtin_amdgcn_global_load_lds(
            (const __attribute__((address_space(1))) void*)(Kg + (long)row * CC + scol * 8),
            (__attribute__((address_space(3))) void*)(dK + c * 8), 16, 0, 0);
        __builtin_amdgcn_global_load_lds(
            (const __attribute__((address_space(1))) void*)(Vg + (long)row * MM + scol * 8),
            (__attribute__((address_space(3))) void*)(dV + c * 8), 16, 0, 0);
    }
}

#define PSTR 68   // P row stride (u16): 136B -> 8B-aligned stores, ~2-way banks

__global__ __launch_bounds__(128) void attn_fwd(const u16* __restrict__ Q,
                                                const u16* __restrict__ Kb,
                                                const u16* __restrict__ Vt,
                                                u16* __restrict__ O) {
    __shared__ u16 sK[2][64 * 64];
    __shared__ u16 sV[2][64 * 64];
    __shared__ u16 sP[2][32 * PSTR];
    int lane = threadIdx.x & 63;
    int w = threadIdx.x >> 6;           // 0..1
    int bh = blockIdx.x & 31;           // same bh -> same XCD
    int g = 31 - (blockIdx.x >> 5);     // descending work (LPT)
    int h = bh & 15, b = bh >> 4;
    int l31 = lane & 31, h5 = lane >> 5;

    int qt = 2 * g + w;                 // q-tile of 32 rows
    int q0 = qt * 32;
    int qg = q0 + l31;                  // this lane's q row
    int ntiles = g + 1;

    const u16* Kgb = Kb + (long)(b * TT) * CC + h * SS;
    const u16* Vgb = Vt + (long)(h * SS) * MM + b * TT;
    u16* Pw = sP[w];

    // Q fragments (B operand): col=l31 (q), k = m*16 + h5*8 + j
    const u16* qrow = Q + (long)(b * TT + qg) * CC + h * SS + h5 * 8;
    bf16x8 qf[4];
#pragma unroll
    for (int m = 0; m < 4; ++m) qf[m] = *(const bf16x8*)(qrow + m * 16);

    f32x16 oa0 = {0.f}, oa1 = {0.f};    // O^T accum: d 0..31 / 32..63, col=q=l31
    float mr = -1e30f, lr = 0.f;

    stage_kv2(Kgb, Vgb, sK[0], sV[0]);

#pragma unroll 1
    for (int t = 0; t < ntiles; ++t) {
        __syncthreads();   // vmcnt drained -> buf[t&1] ready; prev reads fenced
        const u16* cK = sK[t & 1];
        const u16* cV = sV[t & 1];
        if (t + 1 < ntiles)
            stage_kv2(Kgb + (long)(t + 1) * 64 * CC, Vgb + (t + 1) * 64,
                      sK[(t + 1) & 1], sV[(t + 1) & 1]);

        // QK^T swapped: S^T = mfma(A=K, B=Q). s0: kv 0..31, s1: kv 32..63.
        f32x16 s0 = {0.f}, s1 = {0.f};
#pragma unroll
        for (int m = 0; m < 4; ++m) {
            int ch0 = (((m * 2 + h5) ^ (l31 & 7)) << 3);
            bf16x8 k0 = *(const bf16x8*)(cK + l31 * 64 + ch0);
            bf16x8 k1 = *(const bf16x8*)(cK + (32 + l31) * 64 + ch0);
            s0 = MFMA32(k0, qf[m], s0);
            s1 = MFMA32(k1, qf[m], s1);
        }

        if (t == ntiles - 1) {   // diagonal tile: causal mask (kv > q)
            int kvb = t * 64 + 4 * h5;
#pragma unroll
            for (int r = 0; r < 16; ++r) {
                int kv = kvb + (r & 3) + 8 * (r >> 2);
                if (kv > qg) s0[r] = -1e30f;
                if (kv + 32 > qg) s1[r] = -1e30f;
            }
        }

        // tile max: in-lane tree + one partner exchange
        f32x16 m2;
#pragma unroll
        for (int r = 0; r < 16; ++r) m2[r] = fmaxf(s0[r], s1[r]);
#pragma unroll
        for (int r = 0; r < 8; ++r) m2[r] = fmaxf(m2[r], m2[r + 8]);
#pragma unroll
        for (int r = 0; r < 4; ++r) m2[r] = fmaxf(m2[r], m2[r + 4]);
        float tmx = fmaxf(fmaxf(m2[0], m2[1]), fmaxf(m2[2], m2[3]));
        tmx = fmaxf(tmx, __shfl_xor(tmx, 32));

        float mnew = fmaxf(mr, tmx);
        float scl = __expf(mr - mnew);
        lr *= scl;
#pragma unroll
        for (int r = 0; r < 16; ++r) { oa0[r] *= scl; oa1[r] *= scl; }
        mr = mnew;

        f32x16 p0v, p1v;
#pragma unroll
        for (int r = 0; r < 16; ++r) {
            p0v[r] = __expf(s0[r] - mr);
            p1v[r] = __expf(s1[r] - mr);
        }
        f32x16 sm;
#pragma unroll
        for (int r = 0; r < 16; ++r) sm[r] = p0v[r] + p1v[r];
#pragma unroll
        for (int r = 0; r < 8; ++r) sm[r] = sm[r] + sm[r + 8];
#pragma unroll
        for (int r = 0; r < 4; ++r) sm[r] = sm[r] + sm[r + 4];
        float rs = (sm[0] + sm[1]) + (sm[2] + sm[3]);
        rs += __shfl_xor(rs, 32);
        lr += rs;

        // P -> LDS [q=l31][kv], stride PSTR. C-layout: p0v[r] = kv (r&3)+8*(r>>2)+4*h5.
#pragma unroll
        for (int r4 = 0; r4 < 4; ++r4) {
            ushort4 a, c2;
            a.x = f2bf(p0v[r4 * 4 + 0]); a.y = f2bf(p0v[r4 * 4 + 1]);
            a.z = f2bf(p0v[r4 * 4 + 2]); a.w = f2bf(p0v[r4 * 4 + 3]);
            c2.x = f2bf(p1v[r4 * 4 + 0]); c2.y = f2bf(p1v[r4 * 4 + 1]);
            c2.z = f2bf(p1v[r4 * 4 + 2]); c2.w = f2bf(p1v[r4 * 4 + 3]);
            *(ushort4*)(Pw + l31 * PSTR + 8 * r4 + 4 * h5) = a;
            *(ushort4*)(Pw + l31 * PSTR + 32 + 8 * r4 + 4 * h5) = c2;
        }

        // PV: O^T[d][q] += V[d][kv] * P^T[kv][q]; B-frag read: kv = 16s + 8*h5 + j
#pragma unroll
        for (int s = 0; s < 4; ++s) {
            bf16x8 pf = *(const bf16x8*)(Pw + l31 * PSTR + 16 * s + 8 * h5);
            int ch = (((2 * s + h5) ^ (l31 & 7)) << 3);
            bf16x8 v0 = *(const bf16x8*)(cV + l31 * 64 + ch);
            bf16x8 v1 = *(const bf16x8*)(cV + (32 + l31) * 64 + ch);
            oa0 = MFMA32(v0, pf, oa0);
            oa1 = MFMA32(v1, pf, oa1);
        }
    }

    // store O^T -> O[q][d]: oa0[r] = d (r&3)+8*(r>>2)+4*h5, col q = l31
    float inv = 1.0f / lr;
    u16* ob = O + (long)(b * TT + qg) * CC + h * SS;
#pragma unroll
    for (int rq = 0; rq < 4; ++rq) {
        ushort4 a, c2;
        a.x = f2bf(oa0[rq * 4 + 0] * inv); a.y = f2bf(oa0[rq * 4 + 1] * inv);
        a.z = f2bf(oa0[rq * 4 + 2] * inv); a.w = f2bf(oa0[rq * 4 + 3] * inv);
        c2.x = f2bf(oa1[rq * 4 + 0] * inv); c2.y = f2bf(oa1[rq * 4 + 1] * inv);
        c2.z = f2bf(oa1[rq * 4 + 2] * inv); c2.w = f2bf(oa1[rq * 4 + 3] * inv);
        *(ushort4*)(ob + rq * 8 + h5 * 4) = a;
        *(ushort4*)(ob + 32 + rq * 8 + h5 * 4) = c2;
    }
}

// ---------------------------------------------------------------- launch
extern "C" void kernel_launch(void* const* d_in, const int* in_sizes, int n_in,
                              void* d_out, int out_size, void* d_ws, size_t ws_size,
                              hipStream_t stream) {
    const float* x  = (const float*)d_in[0];
    const float* Wq = (const float*)d_in[1];
    const float* Wk = (const float*)d_in[2];
    const float* Wv = (const float*)d_in[3];
    const float* Wo = (const float*)d_in[4];
    const float* bo = (const float*)d_in[5];

    char* ws = (char*)d_ws;
    const size_t MB = 1024 * 1024;
    u16* x_bf  = (u16*)(ws);
    u16* wq_bf = (u16*)(ws + 8 * MB);
    u16* wk_bf = (u16*)(ws + 10 * MB);
    u16* wv_bf = (u16*)(ws + 12 * MB);
    u16* wo_bf = (u16*)(ws + 14 * MB);
    u16* q_bf  = (u16*)(ws + 16 * MB);
    u16* k_bf  = (u16*)(ws + 24 * MB);
    u16* vt_bf = (u16*)(ws + 32 * MB);   // [1024][4096] transposed V
    u16* at_bf = (u16*)(ws + 40 * MB);

    cast_all<<<dim3(8192), dim3(256), 0, stream>>>(
        (const float4*)x, (const float4*)Wq, (const float4*)Wk,
        (const float4*)Wv, (const float4*)Wo,
        (ushort4*)x_bf, (ushort4*)wq_bf, (ushort4*)wk_bf,
        (ushort4*)wv_bf, (ushort4*)wo_bf);

    qkv_gemm<<<dim3(768), dim3(256), 0, stream>>>(x_bf, wq_bf, wk_bf, wv_bf,
                                                  q_bf, k_bf, vt_bf);

    attn_fwd<<<dim3(1024), dim3(128), 0, stream>>>(q_bf, k_bf, vt_bf, at_bf);

    out_gemm<<<dim3(256), dim3(256), 0, stream>>>(at_bf, wo_bf, bo, (float*)d_out);
}

// Round 6
// 122.987 us; speedup vs baseline: 4.3763x; 1.0452x over previous
//
#include <hip/hip_runtime.h>

// Problem constants: B=2, T=2048, C=1024, H=16, S=64
#define BB 2
#define TT 2048
#define CC 1024
#define HH 16
#define SS 64
#define MM (BB * TT)   // 4096

typedef unsigned short u16;
typedef __bf16 bf16x8 __attribute__((ext_vector_type(8)));
typedef float f32x4 __attribute__((ext_vector_type(4)));
typedef float f32x16 __attribute__((ext_vector_type(16)));

#define MFMA16(a, b, c) __builtin_amdgcn_mfma_f32_16x16x32_bf16((a), (b), (c), 0, 0, 0)
#define MFMA32(a, b, c) __builtin_amdgcn_mfma_f32_32x32x16_bf16((a), (b), (c), 0, 0, 0)
// v_cvt_pk_bf16_f32: D[15:0]=bf16(S0), D[31:16]=bf16(S1)
#define CVTPK(d, a, b) asm("v_cvt_pk_bf16_f32 %0, %1, %2" : "=v"(d) : "v"(a), "v"(b))

__device__ inline u16 f2bf(float f) {
    union { float f; unsigned u; } v;
    v.f = f;
    unsigned r = v.u + 0x7FFFu + ((v.u >> 16) & 1u);
    return (u16)(r >> 16);
}

// ---------------------------------------------------------------- fused casts
__global__ __launch_bounds__(256) void cast_all(
    const float4* __restrict__ x,  const float4* __restrict__ wq,
    const float4* __restrict__ wk, const float4* __restrict__ wv,
    const float4* __restrict__ wo,
    ushort4* __restrict__ xo, ushort4* __restrict__ qo,
    ushort4* __restrict__ ko, ushort4* __restrict__ vo,
    ushort4* __restrict__ oo) {
    int bid = blockIdx.x;
    const float4* src; ushort4* dst; int i;
    if (bid < 4096) {
        src = x; dst = xo; i = bid * 256 + threadIdx.x;
    } else {
        int s = (bid - 4096) >> 10;
        int r = (bid - 4096) & 1023;
        src = (s == 0) ? wq : (s == 1) ? wk : (s == 2) ? wv : wo;
        dst = (s == 0) ? qo : (s == 1) ? ko : (s == 2) ? vo : oo;
        i = r * 256 + threadIdx.x;
    }
    float4 v = src[i];
    ushort4 o;
    o.x = f2bf(v.x); o.y = f2bf(v.y); o.z = f2bf(v.z); o.w = f2bf(v.w);
    dst[i] = o;
}

// ---------------------------------------------------------------- 128x128 GEMM core
__device__ __forceinline__ void stage_tile(const u16* __restrict__ g, int row0, int k0,
                                           u16* lds) {
    int t = threadIdx.x;
#pragma unroll
    for (int q = 0; q < 2; ++q) {
        int idx = q * 256 + t;
        int row = idx >> 2;
        int chunk = (idx & 3) ^ (row & 3);
        const u16* src = g + (long)(row0 + row) * CC + k0 + chunk * 8;
        __builtin_amdgcn_global_load_lds(
            (const __attribute__((address_space(1))) void*)src,
            (__attribute__((address_space(3))) void*)(lds + idx * 8), 16, 0, 0);
    }
}

__device__ __forceinline__ void gemm_core(const u16* __restrict__ A,
                                          const u16* __restrict__ Bt,
                                          int blkM, int blkN,
                                          u16* sA0, u16* sB0, u16* sA1, u16* sB1,
                                          f32x4 (&acc)[4][4]) {
    int lane = threadIdx.x & 63;
    int w = threadIdx.x >> 6;
    int wr = w >> 1, wc = w & 1;
    int l15 = lane & 15;
    int hi = lane >> 4;

#pragma unroll
    for (int m = 0; m < 4; ++m)
#pragma unroll
        for (int n = 0; n < 4; ++n) acc[m][n] = (f32x4){0.f, 0.f, 0.f, 0.f};

    stage_tile(A, blkM * 128, 0, sA0);
    stage_tile(Bt, blkN * 128, 0, sB0);

    for (int kt = 0; kt < CC / 32; ++kt) {
        __syncthreads();
        u16* cA = (kt & 1) ? sA1 : sA0;
        u16* cB = (kt & 1) ? sB1 : sB0;
        if (kt + 1 < CC / 32) {
            u16* nA = (kt & 1) ? sA0 : sA1;
            u16* nB = (kt & 1) ? sB0 : sB1;
            stage_tile(A, blkM * 128, (kt + 1) * 32, nA);
            stage_tile(Bt, blkN * 128, (kt + 1) * 32, nB);
        }
        bf16x8 af[4], bfr[4];
#pragma unroll
        for (int m = 0; m < 4; ++m) {
            int row = wr * 64 + m * 16 + l15;
            af[m] = *(const bf16x8*)(cA + row * 32 + ((hi ^ (row & 3)) << 3));
        }
#pragma unroll
        for (int n = 0; n < 4; ++n) {
            int row = wc * 64 + n * 16 + l15;
            bfr[n] = *(const bf16x8*)(cB + row * 32 + ((hi ^ (row & 3)) << 3));
        }
#pragma unroll
        for (int m = 0; m < 4; ++m)
#pragma unroll
            for (int n = 0; n < 4; ++n)
                acc[m][n] = MFMA16(af[m], bfr[n], acc[m][n]);
    }
}

__global__ __launch_bounds__(256) void qkv_gemm(const u16* __restrict__ xb,
                                                const u16* __restrict__ wqb,
                                                const u16* __restrict__ wkb,
                                                const u16* __restrict__ wvb,
                                                u16* __restrict__ qo,
                                                u16* __restrict__ ko,
                                                u16* __restrict__ vt) {
    __shared__ u16 smem[4][128 * 32];
    int seg = blockIdx.x >> 8;
    int bid = blockIdx.x & 255;
    int blkM = bid & 31, blkN = bid >> 5;
    const u16* Bt = (seg == 0) ? wqb : (seg == 1) ? wkb : wvb;
    f32x4 acc[4][4];
    gemm_core(xb, Bt, blkM, blkN, smem[0], smem[1], smem[2], smem[3], acc);

    int lane = threadIdx.x & 63;
    int w = threadIdx.x >> 6, wr = w >> 1, wc = w & 1;
    int l15 = lane & 15, hi = lane >> 4;
    int r0 = blkM * 128 + wr * 64 + hi * 4;
    int c0 = blkN * 128 + wc * 64 + l15;

    if (seg == 2) {
#pragma unroll
        for (int m = 0; m < 4; ++m)
#pragma unroll
            for (int n = 0; n < 4; ++n) {
                ushort4 p;
                p.x = f2bf(acc[m][n][0]); p.y = f2bf(acc[m][n][1]);
                p.z = f2bf(acc[m][n][2]); p.w = f2bf(acc[m][n][3]);
                *(ushort4*)(vt + (long)(c0 + n * 16) * MM + r0 + m * 16) = p;
            }
    } else {
        u16* dst = (seg == 0) ? qo : ko;
        // Q pre-scaled by 1/sqrt(64) * log2(e): exp2-domain softmax
        float sc = (seg == 0) ? 0.18033688011112042f : 1.0f;
#pragma unroll
        for (int m = 0; m < 4; ++m)
#pragma unroll
            for (int n = 0; n < 4; ++n)
#pragma unroll
                for (int i = 0; i < 4; ++i)
                    dst[(long)(r0 + m * 16 + i) * CC + c0 + n * 16] =
                        f2bf(acc[m][n][i] * sc);
    }
}

__global__ __launch_bounds__(256) void out_gemm(const u16* __restrict__ at,
                                                const u16* __restrict__ wob,
                                                const float* __restrict__ bias,
                                                float* __restrict__ out) {
    __shared__ u16 smem[4][128 * 32];
    int bid = blockIdx.x;
    int blkM = bid & 31, blkN = bid >> 5;
    f32x4 acc[4][4];
    gemm_core(at, wob, blkM, blkN, smem[0], smem[1], smem[2], smem[3], acc);

    int lane = threadIdx.x & 63;
    int w = threadIdx.x >> 6, wr = w >> 1, wc = w & 1;
    int l15 = lane & 15, hi = lane >> 4;
    int r0 = blkM * 128 + wr * 64 + hi * 4;
    int c0 = blkN * 128 + wc * 64 + l15;
#pragma unroll
    for (int n = 0; n < 4; ++n) {
        int c = c0 + n * 16;
        float bv = bias[c];
#pragma unroll
        for (int m = 0; m < 4; ++m)
#pragma unroll
            for (int i = 0; i < 4; ++i)
                out[(long)(r0 + m * 16 + i) * CC + c] = acc[m][n][i] + bv;
    }
}

// ---------------------------------------------------------------- flash attention v6
// = v5 structure (swapped QK^T 32x32x16, in-reg softmax, LDS P roundtrip)
// + exp2-domain softmax (Q pre-scaled by log2e/8)
// + defer-max rescale (THR=8 in exp2 domain -> P <= 256)
// + v_cvt_pk_bf16_f32 packing for P-store and O-store
__device__ __forceinline__ void stage_kv2(const u16* __restrict__ Kg,
                                          const u16* __restrict__ Vg,
                                          u16* dK, u16* dV) {
    int t = threadIdx.x;   // 0..127
#pragma unroll
    for (int q = 0; q < 4; ++q) {
        int c = q * 128 + t;           // 16B chunk 0..511
        int row = c >> 3, col = c & 7;
        int scol = col ^ (row & 7);
        __builtin_amdgcn_global_load_lds(
            (const __attribute__((address_space(1))) void*)(Kg + (long)row * CC + scol * 8),
            (__attribute__((address_space(3))) void*)(dK + c * 8), 16, 0, 0);
        __builtin_amdgcn_global_load_lds(
            (const __attribute__((address_space(1))) void*)(Vg + (long)row * MM + scol * 8),
            (__attribute__((address_space(3))) void*)(dV + c * 8), 16, 0, 0);
    }
}

#define PSTR 68   // P row stride (u16): 136B -> 8B-aligned stores, ~2-way banks

__global__ __launch_bounds__(128) void attn_fwd(const u16* __restrict__ Q,
                                                const u16* __restrict__ Kb,
                                                const u16* __restrict__ Vt,
                                                u16* __restrict__ O) {
    __shared__ u16 sK[2][64 * 64];
    __shared__ u16 sV[2][64 * 64];
    __shared__ u16 sP[2][32 * PSTR];
    int lane = threadIdx.x & 63;
    int w = threadIdx.x >> 6;           // 0..1
    int bh = blockIdx.x & 31;           // same bh -> same XCD
    int g = 31 - (blockIdx.x >> 5);     // descending work (LPT)
    int h = bh & 15, b = bh >> 4;
    int l31 = lane & 31, h5 = lane >> 5;

    int qt = 2 * g + w;                 // q-tile of 32 rows
    int q0 = qt * 32;
    int qg = q0 + l31;                  // this lane's q row
    int ntiles = g + 1;

    const u16* Kgb = Kb + (long)(b * TT) * CC + h * SS;
    const u16* Vgb = Vt + (long)(h * SS) * MM + b * TT;
    u16* Pw = sP[w];

    // Q fragments (B operand): col=l31 (q), k = m*16 + h5*8 + j
    const u16* qrow = Q + (long)(b * TT + qg) * CC + h * SS + h5 * 8;
    bf16x8 qf[4];
#pragma unroll
    for (int m = 0; m < 4; ++m) qf[m] = *(const bf16x8*)(qrow + m * 16);

    f32x16 oa0 = {0.f}, oa1 = {0.f};    // O^T accum: d 0..31 / 32..63, col=q=l31
    float mr = -1e30f, lr = 0.f;

    stage_kv2(Kgb, Vgb, sK[0], sV[0]);

#pragma unroll 1
    for (int t = 0; t < ntiles; ++t) {
        __syncthreads();   // vmcnt drained -> buf[t&1] ready; prev reads fenced
        const u16* cK = sK[t & 1];
        const u16* cV = sV[t & 1];
        if (t + 1 < ntiles)
            stage_kv2(Kgb + (long)(t + 1) * 64 * CC, Vgb + (t + 1) * 64,
                      sK[(t + 1) & 1], sV[(t + 1) & 1]);

        // QK^T swapped: S^T = mfma(A=K, B=Q). s0: kv 0..31, s1: kv 32..63.
        f32x16 s0 = {0.f}, s1 = {0.f};
#pragma unroll
        for (int m = 0; m < 4; ++m) {
            int ch0 = (((m * 2 + h5) ^ (l31 & 7)) << 3);
            bf16x8 k0 = *(const bf16x8*)(cK + l31 * 64 + ch0);
            bf16x8 k1 = *(const bf16x8*)(cK + (32 + l31) * 64 + ch0);
            s0 = MFMA32(k0, qf[m], s0);
            s1 = MFMA32(k1, qf[m], s1);
        }

        if (t == ntiles - 1) {   // diagonal tile: causal mask (kv > q)
            int kvb = t * 64 + 4 * h5;
#pragma unroll
            for (int r = 0; r < 16; ++r) {
                int kv = kvb + (r & 3) + 8 * (r >> 2);
                if (kv > qg) s0[r] = -1e30f;
                if (kv + 32 > qg) s1[r] = -1e30f;
            }
        }

        // tile max: in-lane tree + one partner exchange
        f32x16 m2;
#pragma unroll
        for (int r = 0; r < 16; ++r) m2[r] = fmaxf(s0[r], s1[r]);
#pragma unroll
        for (int r = 0; r < 8; ++r) m2[r] = fmaxf(m2[r], m2[r + 8]);
#pragma unroll
        for (int r = 0; r < 4; ++r) m2[r] = fmaxf(m2[r], m2[r + 4]);
        float tmx = fmaxf(fmaxf(m2[0], m2[1]), fmaxf(m2[2], m2[3]));
        tmx = fmaxf(tmx, __shfl_xor(tmx, 32));

        // defer-max: rescale only when tile max exceeds running max by > 8
        if (!__all(tmx <= mr + 8.0f)) {
            float mnew = fmaxf(mr, tmx);
            float scl = __builtin_amdgcn_exp2f(mr - mnew);
            lr *= scl;
#pragma unroll
            for (int r = 0; r < 16; ++r) { oa0[r] *= scl; oa1[r] *= scl; }
            mr = mnew;
        }

        // P = exp2(S - mr), bounded by 2^8
        f32x16 p0v, p1v;
#pragma unroll
        for (int r = 0; r < 16; ++r) {
            p0v[r] = __builtin_amdgcn_exp2f(s0[r] - mr);
            p1v[r] = __builtin_amdgcn_exp2f(s1[r] - mr);
        }
        f32x16 sm;
#pragma unroll
        for (int r = 0; r < 16; ++r) sm[r] = p0v[r] + p1v[r];
#pragma unroll
        for (int r = 0; r < 8; ++r) sm[r] = sm[r] + sm[r + 8];
#pragma unroll
        for (int r = 0; r < 4; ++r) sm[r] = sm[r] + sm[r + 4];
        float rs = (sm[0] + sm[1]) + (sm[2] + sm[3]);
        rs += __shfl_xor(rs, 32);
        lr += rs;

        // P -> LDS [q=l31][kv], stride PSTR; packed via cvt_pk (low u16 = src0)
#pragma unroll
        for (int r4 = 0; r4 < 4; ++r4) {
            unsigned a0, a1, c0, c1;
            CVTPK(a0, p0v[r4 * 4 + 0], p0v[r4 * 4 + 1]);
            CVTPK(a1, p0v[r4 * 4 + 2], p0v[r4 * 4 + 3]);
            CVTPK(c0, p1v[r4 * 4 + 0], p1v[r4 * 4 + 1]);
            CVTPK(c1, p1v[r4 * 4 + 2], p1v[r4 * 4 + 3]);
            uint2 ua, uc;
            ua.x = a0; ua.y = a1; uc.x = c0; uc.y = c1;
            *(uint2*)(Pw + l31 * PSTR + 8 * r4 + 4 * h5) = ua;
            *(uint2*)(Pw + l31 * PSTR + 32 + 8 * r4 + 4 * h5) = uc;
        }

        // PV: O^T[d][q] += V[d][kv] * P^T[kv][q]; B-frag read: kv = 16s + 8*h5 + j
#pragma unroll
        for (int s = 0; s < 4; ++s) {
            bf16x8 pf = *(const bf16x8*)(Pw + l31 * PSTR + 16 * s + 8 * h5);
            int ch = (((2 * s + h5) ^ (l31 & 7)) << 3);
            bf16x8 v0 = *(const bf16x8*)(cV + l31 * 64 + ch);
            bf16x8 v1 = *(const bf16x8*)(cV + (32 + l31) * 64 + ch);
            oa0 = MFMA32(v0, pf, oa0);
            oa1 = MFMA32(v1, pf, oa1);
        }
    }

    // store O^T -> O[q][d]: oa0[r] = d (r&3)+8*(r>>2)+4*h5, col q = l31
    float inv = 1.0f / lr;
    u16* ob = O + (long)(b * TT + qg) * CC + h * SS;
#pragma unroll
    for (int rq = 0; rq < 4; ++rq) {
        unsigned a0, a1, c0, c1;
        CVTPK(a0, oa0[rq * 4 + 0] * inv, oa0[rq * 4 + 1] * inv);
        CVTPK(a1, oa0[rq * 4 + 2] * inv, oa0[rq * 4 + 3] * inv);
        CVTPK(c0, oa1[rq * 4 + 0] * inv, oa1[rq * 4 + 1] * inv);
        CVTPK(c1, oa1[rq * 4 + 2] * inv, oa1[rq * 4 + 3] * inv);
        uint2 ua, uc;
        ua.x = a0; ua.y = a1; uc.x = c0; uc.y = c1;
        *(uint2*)(ob + rq * 8 + h5 * 4) = ua;
        *(uint2*)(ob + 32 + rq * 8 + h5 * 4) = uc;
    }
}

// ---------------------------------------------------------------- launch
extern "C" void kernel_launch(void* const* d_in, const int* in_sizes, int n_in,
                              void* d_out, int out_size, void* d_ws, size_t ws_size,
                              hipStream_t stream) {
    const float* x  = (const float*)d_in[0];
    const float* Wq = (const float*)d_in[1];
    const float* Wk = (const float*)d_in[2];
    const float* Wv = (const float*)d_in[3];
    const float* Wo = (const float*)d_in[4];
    const float* bo = (const float*)d_in[5];

    char* ws = (char*)d_ws;
    const size_t MB = 1024 * 1024;
    u16* x_bf  = (u16*)(ws);
    u16* wq_bf = (u16*)(ws + 8 * MB);
    u16* wk_bf = (u16*)(ws + 10 * MB);
    u16* wv_bf = (u16*)(ws + 12 * MB);
    u16* wo_bf = (u16*)(ws + 14 * MB);
    u16* q_bf  = (u16*)(ws + 16 * MB);
    u16* k_bf  = (u16*)(ws + 24 * MB);
    u16* vt_bf = (u16*)(ws + 32 * MB);   // [1024][4096] transposed V
    u16* at_bf = (u16*)(ws + 40 * MB);

    cast_all<<<dim3(8192), dim3(256), 0, stream>>>(
        (const float4*)x, (const float4*)Wq, (const float4*)Wk,
        (const float4*)Wv, (const float4*)Wo,
        (ushort4*)x_bf, (ushort4*)wq_bf, (ushort4*)wk_bf,
        (ushort4*)wv_bf, (ushort4*)wo_bf);

    qkv_gemm<<<dim3(768), dim3(256), 0, stream>>>(x_bf, wq_bf, wk_bf, wv_bf,
                                                  q_bf, k_bf, vt_bf);

    attn_fwd<<<dim3(1024), dim3(128), 0, stream>>>(q_bf, k_bf, vt_bf, at_bf);

    out_gemm<<<dim3(256), dim3(256), 0, stream>>>(at_bf, wo_bf, bo, (float*)d_out);
}